// Round 1
// baseline (339.411 us; speedup 1.0000x reference)
//
#include <hip/hip_runtime.h>

typedef __attribute__((ext_vector_type(8))) short s8bf;   // 8 x bf16 (as i16)
typedef __attribute__((ext_vector_type(4))) float f4;
typedef __attribute__((ext_vector_type(4))) short s4;

#define HQ 32
#define HK 8
#define DH 128
#define BQ 64
#define BK 64
#define KPAD 136   // 128 + 8: row stride -> 272B -> 4-bank shift/row -> 2-way (free)
#define VPAD 72    // 64 + 8
#define PPAD 72

static __device__ __forceinline__ short f2bf(float f) {
  unsigned u = __builtin_bit_cast(unsigned, f);
  u = (u + 0x7FFFu + ((u >> 16) & 1u)) >> 16;   // RNE
  return (short)u;
}

__launch_bounds__(256, 2)
__global__ void fa_kernel(const float* __restrict__ qg, const float* __restrict__ kg,
                          const float* __restrict__ vg, float* __restrict__ out,
                          int L) {
  __shared__ short Kl[BK * KPAD];
  __shared__ short Vt[DH * VPAD];
  __shared__ short Pl[4 * 16 * PPAD];

  const int qt   = blockIdx.x;
  const int h    = blockIdx.y;
  const int b    = blockIdx.z;
  const int g    = h >> 2;              // kv head (GQA r=4)
  const int tid  = threadIdx.x;
  const int wave = tid >> 6;
  const int lane = tid & 63;
  const int l16  = lane & 15;
  const int quad = lane >> 4;

  const int seq0 = b * L;
  const int q0   = qt * BQ;

  // ---- Q fragments (A-layout: m=l16, k=quad*8+j), kept in registers for all K-tiles
  const int qrow = q0 + wave * 16 + l16;
  const float* qp = qg + ((size_t)(seq0 + qrow) * HQ + h) * DH;
  s8bf qf[4];
#pragma unroll
  for (int dk = 0; dk < 4; ++dk) {
    const float* p = qp + dk * 32 + quad * 8;
    f4 a = *(const f4*)(p);
    f4 c = *(const f4*)(p + 4);
    s8bf t;
    t[0] = f2bf(a[0]); t[1] = f2bf(a[1]); t[2] = f2bf(a[2]); t[3] = f2bf(a[3]);
    t[4] = f2bf(c[0]); t[5] = f2bf(c[1]); t[6] = f2bf(c[2]); t[7] = f2bf(c[3]);
    qf[dk] = t;
  }

  float m[4], lsum[4];
  f4 oacc[8];
#pragma unroll
  for (int i = 0; i < 4; ++i) { m[i] = -1e30f; lsum[i] = 0.0f; }
#pragma unroll
  for (int dt = 0; dt < 8; ++dt) oacc[dt] = (f4)(0.0f);

  const float scale = 0.08838834764831845f;  // 1/sqrt(128)

  for (int kt = 0; kt <= qt; ++kt) {
    const int k0 = kt * BK;
    __syncthreads();  // all waves done reading previous K/V

    // ---- stage K tile: 64 keys x 128 d, f32 -> bf16, coalesced float4 loads
    {
      const float* kbase = kg + ((size_t)(seq0 + k0) * HK + g) * DH;
#pragma unroll
      for (int it = 0; it < 8; ++it) {
        int e = tid * 4 + it * 1024;
        int row = e >> 7, col = e & 127;
        f4 x = *(const f4*)(kbase + (size_t)row * HK * DH + col);
        s4 s; s[0] = f2bf(x[0]); s[1] = f2bf(x[1]); s[2] = f2bf(x[2]); s[3] = f2bf(x[3]);
        *(s4*)&Kl[row * KPAD + col] = s;
      }
      const float* vbase = vg + ((size_t)(seq0 + k0) * HK + g) * DH;
#pragma unroll
      for (int it = 0; it < 8; ++it) {
        int e = tid * 4 + it * 1024;
        int row = e >> 7, col = e & 127;   // row = key, col = d
        f4 x = *(const f4*)(vbase + (size_t)row * HK * DH + col);
        Vt[(col + 0) * VPAD + row] = f2bf(x[0]);
        Vt[(col + 1) * VPAD + row] = f2bf(x[1]);
        Vt[(col + 2) * VPAD + row] = f2bf(x[2]);
        Vt[(col + 3) * VPAD + row] = f2bf(x[3]);
      }
    }
    __syncthreads();

    // ---- S = Q K^T : per wave 16 (q) x 64 (keys)
    f4 sacc[4];
#pragma unroll
    for (int ct = 0; ct < 4; ++ct) sacc[ct] = (f4)(0.0f);
#pragma unroll
    for (int dk = 0; dk < 4; ++dk) {
#pragma unroll
      for (int ct = 0; ct < 4; ++ct) {
        s8bf kf = *(const s8bf*)&Kl[(ct * 16 + l16) * KPAD + dk * 32 + quad * 8];
        sacc[ct] = __builtin_amdgcn_mfma_f32_16x16x32_bf16(qf[dk], kf, sacc[ct], 0, 0, 0);
      }
    }

    // ---- scale + causal mask (only diagonal tile needs it)
    if (kt == qt) {
#pragma unroll
      for (int ct = 0; ct < 4; ++ct)
#pragma unroll
        for (int i = 0; i < 4; ++i) {
          int rl = wave * 16 + quad * 4 + i;   // local row in tile (q0 == k0)
          int cl = ct * 16 + l16;
          float s = sacc[ct][i] * scale;
          sacc[ct][i] = (cl > rl) ? -1e30f : s;
        }
    } else {
#pragma unroll
      for (int ct = 0; ct < 4; ++ct)
#pragma unroll
        for (int i = 0; i < 4; ++i) sacc[ct][i] *= scale;
    }

    // ---- online softmax (row spread over 16 lanes: same quad, l16 = col)
    float mnew[4], alpha[4];
#pragma unroll
    for (int i = 0; i < 4; ++i) {
      float r = fmaxf(fmaxf(sacc[0][i], sacc[1][i]), fmaxf(sacc[2][i], sacc[3][i]));
      r = fmaxf(r, __shfl_xor(r, 1));
      r = fmaxf(r, __shfl_xor(r, 2));
      r = fmaxf(r, __shfl_xor(r, 4));
      r = fmaxf(r, __shfl_xor(r, 8));
      mnew[i] = fmaxf(m[i], r);
      alpha[i] = __expf(m[i] - mnew[i]);
      m[i] = mnew[i];
    }
#pragma unroll
    for (int i = 0; i < 4; ++i) {
      float rs = 0.0f;
#pragma unroll
      for (int ct = 0; ct < 4; ++ct) {
        float pv = __expf(sacc[ct][i] - mnew[i]);
        sacc[ct][i] = pv;
        rs += pv;
      }
      rs += __shfl_xor(rs, 1);
      rs += __shfl_xor(rs, 2);
      rs += __shfl_xor(rs, 4);
      rs += __shfl_xor(rs, 8);
      lsum[i] = lsum[i] * alpha[i] + rs;
#pragma unroll
      for (int dt = 0; dt < 8; ++dt) oacc[dt][i] *= alpha[i];
    }

    // ---- P: C-layout -> LDS -> A-layout (per-wave region, wave-internal dep only)
    short* pw = &Pl[wave * 16 * PPAD];
#pragma unroll
    for (int ct = 0; ct < 4; ++ct)
#pragma unroll
      for (int i = 0; i < 4; ++i)
        pw[(quad * 4 + i) * PPAD + ct * 16 + l16] = f2bf(sacc[ct][i]);
    asm volatile("s_waitcnt lgkmcnt(0)" ::: "memory");

    // ---- O += P V : 8 d-tiles x 2 k-steps
#pragma unroll
    for (int ks = 0; ks < 2; ++ks) {
      s8bf pf = *(const s8bf*)&pw[l16 * PPAD + ks * 32 + quad * 8];
#pragma unroll
      for (int dt = 0; dt < 8; ++dt) {
        s8bf vf = *(const s8bf*)&Vt[(dt * 16 + l16) * VPAD + ks * 32 + quad * 8];
        oacc[dt] = __builtin_amdgcn_mfma_f32_16x16x32_bf16(pf, vf, oacc[dt], 0, 0, 0);
      }
    }
  }

  // ---- epilogue: O /= l, write fp32
  float* op = out + ((size_t)(seq0 + q0 + wave * 16) * HQ + h) * DH;
#pragma unroll
  for (int i = 0; i < 4; ++i) {
    int r = quad * 4 + i;
    float inv = 1.0f / lsum[i];
#pragma unroll
    for (int dt = 0; dt < 8; ++dt)
      op[(size_t)r * HQ * DH + dt * 16 + l16] = oacc[dt][i] * inv;
  }
}

extern "C" void kernel_launch(void* const* d_in, const int* in_sizes, int n_in,
                              void* d_out, int out_size, void* d_ws, size_t ws_size,
                              hipStream_t stream) {
  const float* q = (const float*)d_in[0];
  const float* k = (const float*)d_in[1];
  const float* v = (const float*)d_in[2];
  float* out = (float*)d_out;

  const int B = in_sizes[3] - 1;                 // cu_seqlens_k has B+1 entries
  const int T = in_sizes[0] / (HQ * DH);
  const int L = T / B;                           // 1024
  const int nq = L / BQ;                         // 16

  dim3 grid(nq, HQ, B);
  fa_kernel<<<grid, 256, 0, stream>>>(q, k, v, out, L);
}

// Round 2
// 237.297 us; speedup vs baseline: 1.4303x; 1.4303x over previous
//
#include <hip/hip_runtime.h>

typedef __attribute__((ext_vector_type(8))) short s8bf;   // 8 x bf16 (as i16)
typedef __attribute__((ext_vector_type(4))) float f4;
typedef __attribute__((ext_vector_type(4))) short s4;

#define HQ 32
#define HK 8
#define DH 128
#define BQ 64
#define BK 64
#define KPAD 136   // shorts; 272B row stride (16B aligned for b128)
#define VPAD 72    // shorts; 144B row stride (16B aligned for b128)
#define PPAD 72

static __device__ __forceinline__ short f2bf(float f) {
  unsigned u = __builtin_bit_cast(unsigned, f);
  u = (u + 0x7FFFu + ((u >> 16) & 1u)) >> 16;   // RNE
  return (short)u;
}

__launch_bounds__(256, 3)
__global__ void fa_kernel(const float* __restrict__ qg, const float* __restrict__ kg,
                          const float* __restrict__ vg, float* __restrict__ out,
                          int L) {
  __shared__ short Kl[BK * KPAD];
  __shared__ short Vt[DH * VPAD];
  __shared__ short Pl[4 * 16 * PPAD];

  // ---- XCD-aware decode: all blocks with id%8==xcd share one kv-head's K/V.
  const int id   = blockIdx.x;            // 0..1023
  const int xcd  = id & 7;
  const int slot = id >> 3;               // 0..127
  const int gidx = xcd + 8 * (slot >> 6); // 0..15  (b*8+g)
  const int j    = slot & 63;
  const int b    = gidx >> 3;
  const int g    = gidx & 7;
  const int idx  = j >> 2;
  const int qt   = (idx < 8) ? idx : (23 - idx);  // fold: CU pairs sum to ~17 tiles
  const int h    = g * 4 + (j & 3);

  const int tid  = threadIdx.x;
  const int wave = tid >> 6;
  const int lane = tid & 63;
  const int l16  = lane & 15;
  const int quad = lane >> 4;

  const int seq0 = b * L;
  const int q0   = qt * BQ;

  const float* kb_ = kg + ((size_t)seq0 * HK + g) * DH;
  const float* vb_ = vg + ((size_t)seq0 * HK + g) * DH;

  // ---- Q fragments (A-layout: m=l16, k=quad*8+j), resident for all K-tiles
  const int qrow = q0 + wave * 16 + l16;
  const float* qp = qg + ((size_t)(seq0 + qrow) * HQ + h) * DH;
  s8bf qf[4];
#pragma unroll
  for (int dk = 0; dk < 4; ++dk) {
    const float* p = qp + dk * 32 + quad * 8;
    f4 a = *(const f4*)(p);
    f4 c = *(const f4*)(p + 4);
    s8bf t;
    t[0] = f2bf(a[0]); t[1] = f2bf(a[1]); t[2] = f2bf(a[2]); t[3] = f2bf(a[3]);
    t[4] = f2bf(c[0]); t[5] = f2bf(c[1]); t[6] = f2bf(c[2]); t[7] = f2bf(c[3]);
    qf[dk] = t;
  }

  float m[4], lsum[4];
  f4 oacc[8];
#pragma unroll
  for (int i = 0; i < 4; ++i) { m[i] = -1e30f; lsum[i] = 0.0f; }
#pragma unroll
  for (int dt = 0; dt < 8; ++dt) oacc[dt] = (f4)(0.0f);

  // scale * log2(e): softmax runs in exp2 domain
  const float qscale = 0.08838834764831845f * 1.4426950408889634f;

  // ---- prefetch registers (16 x float4 = 64 VGPRs)
  f4 kreg[8];
  f4 vreg[2][4];
  const int vkb = tid & 15;        // key block (lanes contiguous along keys)
  const int vdb = tid >> 4;        // d block 0..15

  // issue loads for tile 0
  {
    const float* kbase = kb_;
#pragma unroll
    for (int it = 0; it < 8; ++it) {
      int e = tid * 4 + it * 1024;
      int row = e >> 7, col = e & 127;
      kreg[it] = *(const f4*)(kbase + (size_t)row * HK * DH + col);
    }
    const float* vbase = vb_;
#pragma unroll
    for (int it = 0; it < 2; ++it)
#pragma unroll
      for (int r = 0; r < 4; ++r)
        vreg[it][r] = *(const f4*)(vbase + (size_t)(vkb * 4 + r) * HK * DH + (vdb + 16 * it) * 4);
  }

  for (int kt = 0; kt <= qt; ++kt) {
    __syncthreads();  // previous tile's LDS fully consumed

    // ---- store prefetched tile to LDS (f32 -> bf16)
#pragma unroll
    for (int it = 0; it < 8; ++it) {
      int e = tid * 4 + it * 1024;
      int row = e >> 7, col = e & 127;
      f4 x = kreg[it];
      s4 s; s[0] = f2bf(x[0]); s[1] = f2bf(x[1]); s[2] = f2bf(x[2]); s[3] = f2bf(x[3]);
      *(s4*)&Kl[row * KPAD + col] = s;
    }
#pragma unroll
    for (int it = 0; it < 2; ++it) {
      int D = vdb + 16 * it;       // d quad index 0..31
#pragma unroll
      for (int c = 0; c < 4; ++c) {
        s4 s;
        s[0] = f2bf(vreg[it][0][c]);
        s[1] = f2bf(vreg[it][1][c]);
        s[2] = f2bf(vreg[it][2][c]);
        s[3] = f2bf(vreg[it][3][c]);
        *(s4*)&Vt[(D * 4 + c) * VPAD + vkb * 4] = s;  // b64, keys contiguous: no excess conflict
      }
    }
    __syncthreads();  // tile ready

    // ---- issue next tile's global loads (overlap with compute below)
    if (kt < qt) {
      const float* kbase = kb_ + (size_t)((kt + 1) * BK) * HK * DH;
#pragma unroll
      for (int it = 0; it < 8; ++it) {
        int e = tid * 4 + it * 1024;
        int row = e >> 7, col = e & 127;
        kreg[it] = *(const f4*)(kbase + (size_t)row * HK * DH + col);
      }
      const float* vbase = vb_ + (size_t)((kt + 1) * BK) * HK * DH;
#pragma unroll
      for (int it = 0; it < 2; ++it)
#pragma unroll
        for (int r = 0; r < 4; ++r)
          vreg[it][r] = *(const f4*)(vbase + (size_t)(vkb * 4 + r) * HK * DH + (vdb + 16 * it) * 4);
    }

    // ---- S = Q K^T : per wave 16 (q) x 64 (keys)
    f4 sacc[4];
#pragma unroll
    for (int ct = 0; ct < 4; ++ct) sacc[ct] = (f4)(0.0f);
#pragma unroll
    for (int dk = 0; dk < 4; ++dk) {
#pragma unroll
      for (int ct = 0; ct < 4; ++ct) {
        s8bf kf = *(const s8bf*)&Kl[(ct * 16 + l16) * KPAD + dk * 32 + quad * 8];
        sacc[ct] = __builtin_amdgcn_mfma_f32_16x16x32_bf16(qf[dk], kf, sacc[ct], 0, 0, 0);
      }
    }

    // ---- scale (exp2 domain) + causal mask on the diagonal tile
    if (kt == qt) {
#pragma unroll
      for (int ct = 0; ct < 4; ++ct)
#pragma unroll
        for (int i = 0; i < 4; ++i) {
          int rl = wave * 16 + quad * 4 + i;
          int cl = ct * 16 + l16;
          float s = sacc[ct][i] * qscale;
          sacc[ct][i] = (cl > rl) ? -1e30f : s;
        }
    } else {
#pragma unroll
      for (int ct = 0; ct < 4; ++ct)
#pragma unroll
        for (int i = 0; i < 4; ++i) sacc[ct][i] *= qscale;
    }

    // ---- online softmax (row spread over 16 lanes of the quad)
    float mnew[4];
#pragma unroll
    for (int i = 0; i < 4; ++i) {
      float r = fmaxf(fmaxf(sacc[0][i], sacc[1][i]), fmaxf(sacc[2][i], sacc[3][i]));
      r = fmaxf(r, __shfl_xor(r, 1));
      r = fmaxf(r, __shfl_xor(r, 2));
      r = fmaxf(r, __shfl_xor(r, 4));
      r = fmaxf(r, __shfl_xor(r, 8));
      mnew[i] = fmaxf(m[i], r);
    }
#pragma unroll
    for (int i = 0; i < 4; ++i) {
      float alpha = exp2f(m[i] - mnew[i]);
      m[i] = mnew[i];
      float rs = 0.0f;
#pragma unroll
      for (int ct = 0; ct < 4; ++ct) {
        float pv = exp2f(sacc[ct][i] - mnew[i]);
        sacc[ct][i] = pv;
        rs += pv;
      }
      rs += __shfl_xor(rs, 1);
      rs += __shfl_xor(rs, 2);
      rs += __shfl_xor(rs, 4);
      rs += __shfl_xor(rs, 8);
      lsum[i] = lsum[i] * alpha + rs;
#pragma unroll
      for (int dt = 0; dt < 8; ++dt) oacc[dt][i] *= alpha;
    }

    // ---- P: C-layout -> LDS -> A-layout (per-wave region, wave-internal dep)
    short* pw = &Pl[wave * 16 * PPAD];
#pragma unroll
    for (int ct = 0; ct < 4; ++ct)
#pragma unroll
      for (int i = 0; i < 4; ++i)
        pw[(quad * 4 + i) * PPAD + ct * 16 + l16] = f2bf(sacc[ct][i]);
    asm volatile("s_waitcnt lgkmcnt(0)" ::: "memory");

    // ---- O += P V
#pragma unroll
    for (int ks = 0; ks < 2; ++ks) {
      s8bf pf = *(const s8bf*)&pw[l16 * PPAD + ks * 32 + quad * 8];
#pragma unroll
      for (int dt = 0; dt < 8; ++dt) {
        s8bf vf = *(const s8bf*)&Vt[(dt * 16 + l16) * VPAD + ks * 32 + quad * 8];
        oacc[dt] = __builtin_amdgcn_mfma_f32_16x16x32_bf16(pf, vf, oacc[dt], 0, 0, 0);
      }
    }
  }

  // ---- epilogue: O /= l, fp32 store
  float* op = out + ((size_t)(seq0 + q0 + wave * 16) * HQ + h) * DH;
#pragma unroll
  for (int i = 0; i < 4; ++i) {
    int r = quad * 4 + i;
    float inv = 1.0f / lsum[i];
#pragma unroll
    for (int dt = 0; dt < 8; ++dt)
      op[(size_t)r * HQ * DH + dt * 16 + l16] = oacc[dt][i] * inv;
  }
}

extern "C" void kernel_launch(void* const* d_in, const int* in_sizes, int n_in,
                              void* d_out, int out_size, void* d_ws, size_t ws_size,
                              hipStream_t stream) {
  const float* q = (const float*)d_in[0];
  const float* k = (const float*)d_in[1];
  const float* v = (const float*)d_in[2];
  float* out = (float*)d_out;

  const int B = in_sizes[3] - 1;
  const int T = in_sizes[0] / (HQ * DH);
  const int L = T / B;                  // 1024
  const int nq = L / BQ;                // 16
  const int nblocks = nq * HQ * B;      // 1024

  fa_kernel<<<dim3(nblocks), 256, 0, stream>>>(q, k, v, out, L);
}

// Round 3
// 168.279 us; speedup vs baseline: 2.0169x; 1.4101x over previous
//
#include <hip/hip_runtime.h>

typedef __attribute__((ext_vector_type(8))) short s8bf;   // 8 x bf16 (as i16)
typedef __attribute__((ext_vector_type(4))) float f4;
typedef __attribute__((ext_vector_type(2))) unsigned u2;

#define HQ 32
#define HK 8
#define DH 128
#define BK 64
#define KPAD 136   // shorts; 272B row stride -> uniform bank spread for b128 reads
#define VPAD 72    // shorts; 144B row stride

static __device__ __forceinline__ unsigned pkbf(float a, float b) {
  // round-half-up bf16 pair pack: a -> low16, b -> high16
  unsigned ua = __builtin_bit_cast(unsigned, a) + 0x8000u;
  unsigned ub = __builtin_bit_cast(unsigned, b) + 0x8000u;
  return (ua >> 16) | (ub & 0xffff0000u);
}

union frag_u { s8bf v; unsigned u[4]; };

__launch_bounds__(512, 4)
__global__ void fa_kernel(const float* __restrict__ qg, const float* __restrict__ kg,
                          const float* __restrict__ vg, float* __restrict__ out,
                          int L) {
  __shared__ short Kl[BK * KPAD];   // K[key][d] bf16
  __shared__ short Vt[DH * VPAD];   // V^T[d][key] bf16

  // ---- XCD-aware decode: blocks with id%8==xcd share kv-heads {xcd, xcd+8}
  const int id   = blockIdx.x;             // 0..511
  const int xcd  = id & 7;
  const int slot = id >> 3;                // 0..63
  const int gidx = xcd + 8 * (slot >> 5);  // 0..15 = b*8+g
  const int j    = slot & 31;
  const int b    = gidx >> 3;
  const int g    = gidx & 7;
  const int p    = j >> 2;                 // 0..7 -> q-tile pair (p, 15-p)
  const int h    = g * 4 + (j & 3);

  const int tid  = threadIdx.x;
  const int wave = tid >> 6;               // 0..7
  const int lane = tid & 63;
  const int l16  = lane & 15;
  const int quad = lane >> 4;

  const int qtA = p, qtB = 15 - p;         // qtA < qtB always
  const int myqt   = (wave < 4) ? qtA : qtB;
  const int qtmax  = qtB;
  const int q0     = myqt * 64;
  const int qlocal = (wave & 3) * 16 + l16;  // this lane's q-row within the tile

  const int seq0 = b * L;
  const float* kb_ = kg + ((size_t)seq0 * HK + g) * DH;
  const float* vb_ = vg + ((size_t)seq0 * HK + g) * DH;

  // ---- Q fragment (lane data identical for A- or B-operand use)
  const float* qp = qg + ((size_t)(seq0 + q0 + qlocal) * HQ + h) * DH;
  s8bf qf[4];
#pragma unroll
  for (int dk = 0; dk < 4; ++dk) {
    const float* ptr = qp + dk * 32 + quad * 8;
    f4 a = *(const f4*)(ptr);
    f4 c = *(const f4*)(ptr + 4);
    frag_u t;
    t.u[0] = pkbf(a[0], a[1]); t.u[1] = pkbf(a[2], a[3]);
    t.u[2] = pkbf(c[0], c[1]); t.u[3] = pkbf(c[2], c[3]);
    qf[dk] = t.v;
  }

  float m_ = -1e30f, l_ = 0.0f;
  f4 oacc[8];
#pragma unroll
  for (int dt = 0; dt < 8; ++dt) oacc[dt] = (f4)(0.0f);

  const float qsc = 0.08838834764831845f * 1.4426950408889634f;  // 1/sqrt(128)*log2e

  // ---- prefetch regs: K 4xf4, V 4xf4 per thread (512 threads stage 64x128 each)
  f4 kreg[4], vreg[4];
  const int vkb = tid & 15;      // key group (x4)
  const int vdb = tid >> 4;      // d group 0..31 (x4)

  {
    const float* kbase = kb_;
#pragma unroll
    for (int it = 0; it < 4; ++it) {
      int e = tid * 4 + it * 2048;
      kreg[it] = *(const f4*)(kbase + (size_t)(e >> 7) * HK * DH + (e & 127));
    }
    const float* vbase = vb_;
#pragma unroll
    for (int r = 0; r < 4; ++r)
      vreg[r] = *(const f4*)(vbase + (size_t)(vkb * 4 + r) * HK * DH + vdb * 4);
  }

  for (int kt = 0; kt <= qtmax; ++kt) {
    __syncthreads();   // previous tile fully consumed

    // ---- store staged tile (f32 regs -> packed bf16 LDS)
#pragma unroll
    for (int it = 0; it < 4; ++it) {
      int e = tid * 4 + it * 2048;
      u2 w; w[0] = pkbf(kreg[it][0], kreg[it][1]); w[1] = pkbf(kreg[it][2], kreg[it][3]);
      *(u2*)&Kl[(e >> 7) * KPAD + (e & 127)] = w;
    }
#pragma unroll
    for (int c = 0; c < 4; ++c) {
      u2 w;
      w[0] = pkbf(vreg[0][c], vreg[1][c]);
      w[1] = pkbf(vreg[2][c], vreg[3][c]);
      *(u2*)&Vt[(vdb * 4 + c) * VPAD + vkb * 4] = w;
    }
    __syncthreads();   // tile ready

    // ---- issue next tile's loads (overlap with compute)
    if (kt < qtmax) {
      const float* kbase = kb_ + (size_t)((kt + 1) * BK) * HK * DH;
#pragma unroll
      for (int it = 0; it < 4; ++it) {
        int e = tid * 4 + it * 2048;
        kreg[it] = *(const f4*)(kbase + (size_t)(e >> 7) * HK * DH + (e & 127));
      }
      const float* vbase = vb_ + (size_t)((kt + 1) * BK) * HK * DH;
#pragma unroll
      for (int r = 0; r < 4; ++r)
        vreg[r] = *(const f4*)(vbase + (size_t)(vkb * 4 + r) * HK * DH + vdb * 4);
    }

    if (kt <= myqt) {
      // ---- S^T = K Q^T : lane (quad,l16) holds keys ct*16+quad*4+i for q=l16
      f4 sacc[4];
#pragma unroll
      for (int ct = 0; ct < 4; ++ct) sacc[ct] = (f4)(0.0f);
#pragma unroll
      for (int dk = 0; dk < 4; ++dk) {
#pragma unroll
        for (int ct = 0; ct < 4; ++ct) {
          s8bf kf = *(const s8bf*)&Kl[(ct * 16 + l16) * KPAD + dk * 32 + quad * 8];
          sacc[ct] = __builtin_amdgcn_mfma_f32_16x16x32_bf16(kf, qf[dk], sacc[ct], 0, 0, 0);
        }
      }

      // ---- scale (exp2 domain) + causal mask on the diagonal tile
      if (kt == myqt) {
#pragma unroll
        for (int ct = 0; ct < 4; ++ct)
#pragma unroll
          for (int i = 0; i < 4; ++i) {
            int key = ct * 16 + quad * 4 + i;
            float s = sacc[ct][i] * qsc;
            sacc[ct][i] = (key > qlocal) ? -1e30f : s;
          }
      } else {
#pragma unroll
        for (int ct = 0; ct < 4; ++ct)
#pragma unroll
          for (int i = 0; i < 4; ++i) sacc[ct][i] *= qsc;
      }

      // ---- online softmax: in-lane over 16, then xor16/xor32 across quads
      float r01 = fmaxf(fmaxf(sacc[0][0], sacc[0][1]), fmaxf(sacc[0][2], sacc[0][3]));
      float r23 = fmaxf(fmaxf(sacc[1][0], sacc[1][1]), fmaxf(sacc[1][2], sacc[1][3]));
      float r45 = fmaxf(fmaxf(sacc[2][0], sacc[2][1]), fmaxf(sacc[2][2], sacc[2][3]));
      float r67 = fmaxf(fmaxf(sacc[3][0], sacc[3][1]), fmaxf(sacc[3][2], sacc[3][3]));
      float r = fmaxf(fmaxf(r01, r23), fmaxf(r45, r67));
      r = fmaxf(r, __shfl_xor(r, 16));
      r = fmaxf(r, __shfl_xor(r, 32));
      float mn = fmaxf(m_, r);
      float alpha = exp2f(m_ - mn);
      m_ = mn;

      float rs = 0.0f;
#pragma unroll
      for (int ct = 0; ct < 4; ++ct)
#pragma unroll
        for (int i = 0; i < 4; ++i) {
          float pv = exp2f(sacc[ct][i] - mn);
          sacc[ct][i] = pv;
          rs += pv;
        }
      rs += __shfl_xor(rs, 16);
      rs += __shfl_xor(rs, 32);
      l_ = l_ * alpha + rs;
#pragma unroll
      for (int dt = 0; dt < 8; ++dt) oacc[dt] *= alpha;

      // ---- pack P, in-register transpose to PV B-fragment (cross-quad gather)
      unsigned pk[4][2];
#pragma unroll
      for (int ct = 0; ct < 4; ++ct) {
        pk[ct][0] = pkbf(sacc[ct][0], sacc[ct][1]);
        pk[ct][1] = pkbf(sacc[ct][2], sacc[ct][3]);
      }
      const int srcA = ((quad & 1) << 5) + l16;
      const int srcB = srcA + 16;
      const bool hi = (quad >> 1) != 0;
      frag_u fr[2];
#pragma unroll
      for (int ks = 0; ks < 2; ++ks) {
#pragma unroll
        for (int w = 0; w < 2; ++w) {
          unsigned a0 = (unsigned)__shfl((int)pk[2 * ks][w], srcA);
          unsigned a1 = (unsigned)__shfl((int)pk[2 * ks + 1][w], srcA);
          fr[ks].u[w] = hi ? a1 : a0;
          unsigned b0 = (unsigned)__shfl((int)pk[2 * ks][w], srcB);
          unsigned b1 = (unsigned)__shfl((int)pk[2 * ks + 1][w], srcB);
          fr[ks].u[2 + w] = hi ? b1 : b0;
        }
      }

      // ---- O^T += V^T P^T
#pragma unroll
      for (int ks = 0; ks < 2; ++ks) {
#pragma unroll
        for (int dt = 0; dt < 8; ++dt) {
          s8bf vf = *(const s8bf*)&Vt[(dt * 16 + l16) * VPAD + ks * 32 + quad * 8];
          oacc[dt] = __builtin_amdgcn_mfma_f32_16x16x32_bf16(vf, fr[ks].v, oacc[dt], 0, 0, 0);
        }
      }
    }
  }

  // ---- epilogue: lane (quad,l16) holds O[q=l16][d=dt*16+quad*4+i] -> float4 stores
  float inv = 1.0f / l_;
  float* op = out + ((size_t)(seq0 + q0 + qlocal) * HQ + h) * DH;
#pragma unroll
  for (int dt = 0; dt < 8; ++dt) {
    f4 w;
    w[0] = oacc[dt][0] * inv; w[1] = oacc[dt][1] * inv;
    w[2] = oacc[dt][2] * inv; w[3] = oacc[dt][3] * inv;
    *(f4*)&op[dt * 16 + quad * 4] = w;
  }
}

extern "C" void kernel_launch(void* const* d_in, const int* in_sizes, int n_in,
                              void* d_out, int out_size, void* d_ws, size_t ws_size,
                              hipStream_t stream) {
  const float* q = (const float*)d_in[0];
  const float* k = (const float*)d_in[1];
  const float* v = (const float*)d_in[2];
  float* out = (float*)d_out;

  const int B = in_sizes[3] - 1;
  const int T = in_sizes[0] / (HQ * DH);
  const int L = T / B;                  // 1024
  const int nblocks = (L / 64) / 2 * HQ * B;  // 8 pairs * 32 heads * 2 = 512

  fa_kernel<<<dim3(nblocks), 512, 0, stream>>>(q, k, v, out, L);
}